// Round 1
// baseline (5101.480 us; speedup 1.0000x reference)
//
#include <hip/hip_runtime.h>

// NNConv particle GNN, factored:
//   T[n,h,o] = sum_i x[n,i] * w3[h, i*16+o]   (node-level, kills 16x edge FLOPs)
//   msg[e,o] = sum_h h2[e,h] * T[src,h,o] + xb[src,o]
// BN (training mode) => linear biases b1/b2/own_b1/own_b2 cancel exactly.
// Stats passes recompute layers instead of staging h_pre (cheaper traffic).

#define N_NODES 50000
#define N_EDGES 800000
#define SD 32
#define OC 16
#define HID 32
#define BN_EPS 1e-5f
#define GRID_STATS 1024

__device__ __forceinline__ float f4get(const float4& v, int ii) {
  return ii == 0 ? v.x : ii == 1 ? v.y : ii == 2 ? v.z : v.w;
}

// z[0..31] += (4*I4-row chunk starting at w-row IOFF) dotted with rp rows
template<int I4, int IOFF>
__device__ __forceinline__ void mv_acc(const float4* __restrict__ rp,
                                       const float* __restrict__ wlds,
                                       float z[HID]) {
#pragma unroll
  for (int i4 = 0; i4 < I4; ++i4) {
    float4 rv = rp[i4];
#pragma unroll
    for (int ii = 0; ii < 4; ++ii) {
      float s = f4get(rv, ii);
      const float* wrow = wlds + (IOFF + i4 * 4 + ii) * HID;
#pragma unroll
      for (int h4 = 0; h4 < HID / 4; ++h4) {
        float4 wv = *reinterpret_cast<const float4*>(wrow + h4 * 4);
        z[h4 * 4 + 0] = fmaf(s, wv.x, z[h4 * 4 + 0]);
        z[h4 * 4 + 1] = fmaf(s, wv.y, z[h4 * 4 + 1]);
        z[h4 * 4 + 2] = fmaf(s, wv.z, z[h4 * 4 + 2]);
        z[h4 * 4 + 3] = fmaf(s, wv.w, z[h4 * 4 + 3]);
      }
    }
  }
}

// z = v(32-vector in regs) @ w (32x32 in LDS)
__device__ __forceinline__ void mv_reg(const float* __restrict__ v,
                                       const float* __restrict__ wlds,
                                       float z[HID]) {
#pragma unroll
  for (int h = 0; h < HID; ++h) z[h] = 0.f;
#pragma unroll
  for (int i = 0; i < HID; ++i) {
    float s = v[i];
    const float* wrow = wlds + i * HID;
#pragma unroll
    for (int h4 = 0; h4 < HID / 4; ++h4) {
      float4 wv = *reinterpret_cast<const float4*>(wrow + h4 * 4);
      z[h4 * 4 + 0] = fmaf(s, wv.x, z[h4 * 4 + 0]);
      z[h4 * 4 + 1] = fmaf(s, wv.y, z[h4 * 4 + 1]);
      z[h4 * 4 + 2] = fmaf(s, wv.z, z[h4 * 4 + 2]);
      z[h4 * 4 + 3] = fmaf(s, wv.w, z[h4 * 4 + 3]);
    }
  }
}

// block(256) hierarchical reduce of per-thread sum[32]/sumsq[32] -> 64 global atomics
__device__ __forceinline__ void stats_reduce(const float ssum[HID], const float ssq[HID],
                                             float* __restrict__ gstats,
                                             float* __restrict__ part) {
  int lane = threadIdx.x & 63;
  float mine = 0.f;
#pragma unroll
  for (int q = 0; q < HID; ++q) {
    float v = ssum[q];
#pragma unroll
    for (int m = 32; m >= 1; m >>= 1) v += __shfl_xor(v, m, 64);
    if (lane == q) mine = v;
    float u = ssq[q];
#pragma unroll
    for (int m = 32; m >= 1; m >>= 1) u += __shfl_xor(u, m, 64);
    if (lane == q + 32) mine = u;
  }
  part[(threadIdx.x >> 6) * 64 + lane] = mine;
  __syncthreads();
  if (threadIdx.x < 64) {
    float t = part[threadIdx.x] + part[64 + threadIdx.x] +
              part[128 + threadIdx.x] + part[192 + threadIdx.x];
    atomicAdd(gstats + threadIdx.x, t);
  }
}

// per-block BN scale/shift from accumulated stats (biases cancelled)
__device__ __forceinline__ void bn_params(const float* __restrict__ stats, int off,
                                          float cntInv, const float* __restrict__ g,
                                          const float* __restrict__ be,
                                          float* __restrict__ sc, float* __restrict__ sf) {
  if (threadIdx.x < HID) {
    int h = threadIdx.x;
    float mean = stats[off + h] * cntInv;
    float var = stats[off + HID + h] * cntInv - mean * mean;
    float s = g[h] * rsqrtf(var + BN_EPS);
    sc[h] = s;
    sf[h] = fmaf(-mean, s, be[h]);
  }
}

// K0: per-node T [N,32,16], xb = x@b3-reshaped, agg init = x@root_w + root_b
__global__ __launch_bounds__(256) void k0_nodes(
    const float* __restrict__ x, const float* __restrict__ w3,
    const float* __restrict__ b3, const float* __restrict__ rootw,
    const float* __restrict__ rootb, float* __restrict__ T,
    float* __restrict__ xb, float* __restrict__ agg) {
  __shared__ float xs[16][33];
  int n0 = blockIdx.x * 16;
  for (int f = threadIdx.x; f < 16 * SD; f += 256) {
    int nl = f >> 5, i = f & 31;
    int n = n0 + nl;
    xs[nl][i] = (n < N_NODES) ? x[(size_t)n * SD + i] : 0.f;
  }
  __syncthreads();
  int oH = threadIdx.x & 1;          // which 8-wide half of the 16 o's
  int h = (threadIdx.x >> 1) & 31;   // output row of T
  int ng = threadIdx.x >> 6;         // node group (4 nodes each)
  float acc[4][8];
#pragma unroll
  for (int k = 0; k < 4; ++k)
#pragma unroll
    for (int j = 0; j < 8; ++j) acc[k][j] = 0.f;
  const float* wbase = w3 + h * (SD * OC) + oH * 8;
#pragma unroll
  for (int i = 0; i < SD; ++i) {
    float4 wa = *reinterpret_cast<const float4*>(wbase + i * OC);
    float4 wb = *reinterpret_cast<const float4*>(wbase + i * OC + 4);
#pragma unroll
    for (int k = 0; k < 4; ++k) {
      float xv = xs[ng * 4 + k][i];
      acc[k][0] = fmaf(xv, wa.x, acc[k][0]);
      acc[k][1] = fmaf(xv, wa.y, acc[k][1]);
      acc[k][2] = fmaf(xv, wa.z, acc[k][2]);
      acc[k][3] = fmaf(xv, wa.w, acc[k][3]);
      acc[k][4] = fmaf(xv, wb.x, acc[k][4]);
      acc[k][5] = fmaf(xv, wb.y, acc[k][5]);
      acc[k][6] = fmaf(xv, wb.z, acc[k][6]);
      acc[k][7] = fmaf(xv, wb.w, acc[k][7]);
    }
  }
#pragma unroll
  for (int k = 0; k < 4; ++k) {
    int n = n0 + ng * 4 + k;
    if (n < N_NODES) {
      float4* dstp = reinterpret_cast<float4*>(T + (size_t)n * (HID * OC) + h * OC + oH * 8);
      dstp[0] = make_float4(acc[k][0], acc[k][1], acc[k][2], acc[k][3]);
      dstp[1] = make_float4(acc[k][4], acc[k][5], acc[k][6], acc[k][7]);
    }
  }
  // xb and agg init (root weight + bias)
  int nl = threadIdx.x >> 4, o = threadIdx.x & 15;
  int n = n0 + nl;
  if (n < N_NODES) {
    float a1 = 0.f, a2 = 0.f;
#pragma unroll
    for (int i = 0; i < SD; ++i) {
      float xv = xs[nl][i];
      a1 = fmaf(xv, b3[i * OC + o], a1);
      a2 = fmaf(xv, rootw[i * OC + o], a2);
    }
    xb[(size_t)n * OC + o] = a1;
    agg[(size_t)n * OC + o] = a2 + rootb[o];
  }
}

// K1: msg-MLP layer1 pre-activation stats (no b1 -- cancels in BN)
__global__ __launch_bounds__(256) void k1_msg_bn1(
    const float* __restrict__ ea, const float* __restrict__ w1,
    float* __restrict__ stats) {
  __shared__ float w1s[SD * HID];
  __shared__ float part[256];
  for (int f = threadIdx.x; f < SD * HID; f += 256) w1s[f] = w1[f];
  __syncthreads();
  float ssum[HID], ssq[HID];
#pragma unroll
  for (int h = 0; h < HID; ++h) { ssum[h] = 0.f; ssq[h] = 0.f; }
  for (int e = blockIdx.x * 256 + threadIdx.x; e < N_EDGES; e += GRID_STATS * 256) {
    const float4* rp = reinterpret_cast<const float4*>(ea + (size_t)e * SD);
    float z[HID];
#pragma unroll
    for (int h = 0; h < HID; ++h) z[h] = 0.f;
    mv_acc<8, 0>(rp, w1s, z);
#pragma unroll
    for (int h = 0; h < HID; ++h) {
      ssum[h] += z[h];
      ssq[h] = fmaf(z[h], z[h], ssq[h]);
    }
  }
  stats_reduce(ssum, ssq, stats + 0, part);
}

// K3: recompute layer1 (+BN1+ReLU), layer2 pre-activation stats
__global__ __launch_bounds__(256) void k3_msg_bn2(
    const float* __restrict__ ea, const float* __restrict__ w1,
    const float* __restrict__ w2, const float* __restrict__ g1,
    const float* __restrict__ be1, float* __restrict__ stats) {
  __shared__ float w1s[SD * HID], w2s[HID * HID];
  __shared__ float sc1[HID], sf1[HID];
  __shared__ float part[256];
  for (int f = threadIdx.x; f < SD * HID; f += 256) w1s[f] = w1[f];
  for (int f = threadIdx.x; f < HID * HID; f += 256) w2s[f] = w2[f];
  bn_params(stats, 0, 1.f / N_EDGES, g1, be1, sc1, sf1);
  __syncthreads();
  float ssum[HID], ssq[HID];
#pragma unroll
  for (int h = 0; h < HID; ++h) { ssum[h] = 0.f; ssq[h] = 0.f; }
  for (int e = blockIdx.x * 256 + threadIdx.x; e < N_EDGES; e += GRID_STATS * 256) {
    const float4* rp = reinterpret_cast<const float4*>(ea + (size_t)e * SD);
    float z1[HID];
#pragma unroll
    for (int h = 0; h < HID; ++h) z1[h] = 0.f;
    mv_acc<8, 0>(rp, w1s, z1);
#pragma unroll
    for (int i = 0; i < HID; ++i) z1[i] = fmaxf(0.f, fmaf(z1[i], sc1[i], sf1[i]));
    float z2[HID];
    mv_reg(z1, w2s, z2);
#pragma unroll
    for (int h = 0; h < HID; ++h) {
      ssum[h] += z2[h];
      ssq[h] = fmaf(z2[h], z2[h], ssq[h]);
    }
  }
  stats_reduce(ssum, ssq, stats + 64, part);
}

// K5: full edge message (recompute h1,h2), msg = h2 @ T[src] + xb[src], atomic scatter to agg[dst]
__global__ __launch_bounds__(256) void k5_edge_msg(
    const float* __restrict__ ea, const int* __restrict__ ei,
    const float* __restrict__ w1, const float* __restrict__ w2,
    const float* __restrict__ g1, const float* __restrict__ be1,
    const float* __restrict__ g2, const float* __restrict__ be2,
    const float* __restrict__ T, const float* __restrict__ xb,
    const float* __restrict__ stats, float* __restrict__ agg) {
  __shared__ float w1s[SD * HID], w2s[HID * HID];
  __shared__ float sc1[HID], sf1[HID], sc2[HID], sf2[HID];
  for (int f = threadIdx.x; f < SD * HID; f += 256) w1s[f] = w1[f];
  for (int f = threadIdx.x; f < HID * HID; f += 256) w2s[f] = w2[f];
  bn_params(stats, 0, 1.f / N_EDGES, g1, be1, sc1, sf1);
  bn_params(stats, 64, 1.f / N_EDGES, g2, be2, sc2, sf2);
  __syncthreads();
  int e = blockIdx.x * 256 + threadIdx.x;
  if (e >= N_EDGES) return;
  const float4* rp = reinterpret_cast<const float4*>(ea + (size_t)e * SD);
  float z1[HID];
#pragma unroll
  for (int h = 0; h < HID; ++h) z1[h] = 0.f;
  mv_acc<8, 0>(rp, w1s, z1);
#pragma unroll
  for (int i = 0; i < HID; ++i) z1[i] = fmaxf(0.f, fmaf(z1[i], sc1[i], sf1[i]));
  float z2[HID];
  mv_reg(z1, w2s, z2);
#pragma unroll
  for (int i = 0; i < HID; ++i) z2[i] = fmaxf(0.f, fmaf(z2[i], sc2[i], sf2[i]));
  int src = ei[e];
  int dst = ei[N_EDGES + e];
  const float4* Trow = reinterpret_cast<const float4*>(T + (size_t)src * (HID * OC));
  const float4* xbr = reinterpret_cast<const float4*>(xb + (size_t)src * OC);
  float msg[OC];
#pragma unroll
  for (int o4 = 0; o4 < 4; ++o4) {
    float4 b = xbr[o4];
    msg[o4 * 4 + 0] = b.x; msg[o4 * 4 + 1] = b.y;
    msg[o4 * 4 + 2] = b.z; msg[o4 * 4 + 3] = b.w;
  }
#pragma unroll
  for (int hh = 0; hh < HID; ++hh) {
    float hv = z2[hh];
#pragma unroll
    for (int o4 = 0; o4 < 4; ++o4) {
      float4 tv = Trow[hh * 4 + o4];
      msg[o4 * 4 + 0] = fmaf(hv, tv.x, msg[o4 * 4 + 0]);
      msg[o4 * 4 + 1] = fmaf(hv, tv.y, msg[o4 * 4 + 1]);
      msg[o4 * 4 + 2] = fmaf(hv, tv.z, msg[o4 * 4 + 2]);
      msg[o4 * 4 + 3] = fmaf(hv, tv.w, msg[o4 * 4 + 3]);
    }
  }
  float* arow = agg + (size_t)dst * OC;
#pragma unroll
  for (int o = 0; o < OC; ++o) atomicAdd(arow + o, msg[o]);
}

// K6: own-MLP layer1 stats. combined = [x, messages(=agg)]
__global__ __launch_bounds__(256) void k6_own_bn1(
    const float* __restrict__ x, const float* __restrict__ msgs,
    const float* __restrict__ w1, float* __restrict__ stats) {
  __shared__ float w1s[(SD + OC) * HID];
  __shared__ float part[256];
  for (int f = threadIdx.x; f < (SD + OC) * HID; f += 256) w1s[f] = w1[f];
  __syncthreads();
  float ssum[HID], ssq[HID];
#pragma unroll
  for (int h = 0; h < HID; ++h) { ssum[h] = 0.f; ssq[h] = 0.f; }
  int n = blockIdx.x * 256 + threadIdx.x;
  if (n < N_NODES) {
    const float4* xp = reinterpret_cast<const float4*>(x + (size_t)n * SD);
    const float4* mp = reinterpret_cast<const float4*>(msgs + (size_t)n * OC);
    float z[HID];
#pragma unroll
    for (int h = 0; h < HID; ++h) z[h] = 0.f;
    mv_acc<8, 0>(xp, w1s, z);
    mv_acc<4, SD>(mp, w1s, z);
#pragma unroll
    for (int h = 0; h < HID; ++h) {
      ssum[h] += z[h];
      ssq[h] = fmaf(z[h], z[h], ssq[h]);
    }
  }
  stats_reduce(ssum, ssq, stats + 128, part);
}

// K8: own layer1 (+BN+ReLU) recompute, layer2 stats
__global__ __launch_bounds__(256) void k8_own_bn2(
    const float* __restrict__ x, const float* __restrict__ msgs,
    const float* __restrict__ w1, const float* __restrict__ w2,
    const float* __restrict__ g1, const float* __restrict__ be1,
    float* __restrict__ stats) {
  __shared__ float w1s[(SD + OC) * HID], w2s[HID * HID];
  __shared__ float sc1[HID], sf1[HID];
  __shared__ float part[256];
  for (int f = threadIdx.x; f < (SD + OC) * HID; f += 256) w1s[f] = w1[f];
  for (int f = threadIdx.x; f < HID * HID; f += 256) w2s[f] = w2[f];
  bn_params(stats, 128, 1.f / N_NODES, g1, be1, sc1, sf1);
  __syncthreads();
  float ssum[HID], ssq[HID];
#pragma unroll
  for (int h = 0; h < HID; ++h) { ssum[h] = 0.f; ssq[h] = 0.f; }
  int n = blockIdx.x * 256 + threadIdx.x;
  if (n < N_NODES) {
    const float4* xp = reinterpret_cast<const float4*>(x + (size_t)n * SD);
    const float4* mp = reinterpret_cast<const float4*>(msgs + (size_t)n * OC);
    float z1[HID];
#pragma unroll
    for (int h = 0; h < HID; ++h) z1[h] = 0.f;
    mv_acc<8, 0>(xp, w1s, z1);
    mv_acc<4, SD>(mp, w1s, z1);
#pragma unroll
    for (int i = 0; i < HID; ++i) z1[i] = fmaxf(0.f, fmaf(z1[i], sc1[i], sf1[i]));
    float z2[HID];
    mv_reg(z1, w2s, z2);
#pragma unroll
    for (int h = 0; h < HID; ++h) {
      ssum[h] += z2[h];
      ssq[h] = fmaf(z2[h], z2[h], ssq[h]);
    }
  }
  stats_reduce(ssum, ssq, stats + 192, part);
}

// K10: full own-MLP recompute + final linear (own_b3 kept) -> out
__global__ __launch_bounds__(256) void k10_own_out(
    const float* __restrict__ x, const float* __restrict__ msgs,
    const float* __restrict__ w1, const float* __restrict__ w2,
    const float* __restrict__ w3o, const float* __restrict__ b3o,
    const float* __restrict__ g1, const float* __restrict__ be1,
    const float* __restrict__ g2, const float* __restrict__ be2,
    const float* __restrict__ stats, float* __restrict__ out) {
  __shared__ float w1s[(SD + OC) * HID], w2s[HID * HID], w3s[HID * SD];
  __shared__ float sc1[HID], sf1[HID], sc2[HID], sf2[HID];
  for (int f = threadIdx.x; f < (SD + OC) * HID; f += 256) w1s[f] = w1[f];
  for (int f = threadIdx.x; f < HID * HID; f += 256) w2s[f] = w2[f];
  for (int f = threadIdx.x; f < HID * SD; f += 256) w3s[f] = w3o[f];
  bn_params(stats, 128, 1.f / N_NODES, g1, be1, sc1, sf1);
  bn_params(stats, 192, 1.f / N_NODES, g2, be2, sc2, sf2);
  __syncthreads();
  int n = blockIdx.x * 256 + threadIdx.x;
  if (n >= N_NODES) return;
  const float4* xp = reinterpret_cast<const float4*>(x + (size_t)n * SD);
  const float4* mp = reinterpret_cast<const float4*>(msgs + (size_t)n * OC);
  float z1[HID];
#pragma unroll
  for (int h = 0; h < HID; ++h) z1[h] = 0.f;
  mv_acc<8, 0>(xp, w1s, z1);
  mv_acc<4, SD>(mp, w1s, z1);
#pragma unroll
  for (int i = 0; i < HID; ++i) z1[i] = fmaxf(0.f, fmaf(z1[i], sc1[i], sf1[i]));
  float z2[HID];
  mv_reg(z1, w2s, z2);
#pragma unroll
  for (int i = 0; i < HID; ++i) z2[i] = fmaxf(0.f, fmaf(z2[i], sc2[i], sf2[i]));
  float z3[HID];
  mv_reg(z2, w3s, z3);
  float4* op = reinterpret_cast<float4*>(out + (size_t)n * SD);
#pragma unroll
  for (int j4 = 0; j4 < 8; ++j4) {
    op[j4] = make_float4(z3[j4 * 4 + 0] + b3o[j4 * 4 + 0],
                         z3[j4 * 4 + 1] + b3o[j4 * 4 + 1],
                         z3[j4 * 4 + 2] + b3o[j4 * 4 + 2],
                         z3[j4 * 4 + 3] + b3o[j4 * 4 + 3]);
  }
}

extern "C" void kernel_launch(void* const* d_in, const int* in_sizes, int n_in,
                              void* d_out, int out_size, void* d_ws, size_t ws_size,
                              hipStream_t stream) {
  const float* x    = (const float*)d_in[0];
  const float* ea   = (const float*)d_in[1];
  const int*   ei   = (const int*)d_in[2];
  const float* mw1  = (const float*)d_in[3];
  const float* mg1  = (const float*)d_in[5];
  const float* mbe1 = (const float*)d_in[6];
  const float* mw2  = (const float*)d_in[7];
  const float* mg2  = (const float*)d_in[9];
  const float* mbe2 = (const float*)d_in[10];
  const float* mw3  = (const float*)d_in[11];
  const float* mb3  = (const float*)d_in[12];
  const float* rw   = (const float*)d_in[13];
  const float* rb   = (const float*)d_in[14];
  const float* ow1  = (const float*)d_in[15];
  const float* og1  = (const float*)d_in[17];
  const float* obe1 = (const float*)d_in[18];
  const float* ow2  = (const float*)d_in[19];
  const float* og2  = (const float*)d_in[21];
  const float* obe2 = (const float*)d_in[22];
  const float* ow3  = (const float*)d_in[23];
  const float* ob3  = (const float*)d_in[24];
  float* out = (float*)d_out;

  float* wsf = (float*)d_ws;
  float* stats = wsf;                       // 256 floats (4 BN layers x sum/sumsq)
  float* T = wsf + 256;                     // [N,32,16] = 25.6M floats
  float* xb = T + (size_t)N_NODES * HID * OC;   // [N,16]
  float* agg = xb + (size_t)N_NODES * OC;       // [N,16] (becomes `messages`)

  hipMemsetAsync(stats, 0, 256 * sizeof(float), stream);

  k0_nodes<<<(N_NODES + 15) / 16, 256, 0, stream>>>(x, mw3, mb3, rw, rb, T, xb, agg);
  k1_msg_bn1<<<GRID_STATS, 256, 0, stream>>>(ea, mw1, stats);
  k3_msg_bn2<<<GRID_STATS, 256, 0, stream>>>(ea, mw1, mw2, mg1, mbe1, stats);
  k5_edge_msg<<<(N_EDGES + 255) / 256, 256, 0, stream>>>(
      ea, ei, mw1, mw2, mg1, mbe1, mg2, mbe2, T, xb, stats, agg);
  k6_own_bn1<<<(N_NODES + 255) / 256, 256, 0, stream>>>(x, agg, ow1, stats);
  k8_own_bn2<<<(N_NODES + 255) / 256, 256, 0, stream>>>(x, agg, ow1, ow2, og1, obe1, stats);
  k10_own_out<<<(N_NODES + 255) / 256, 256, 0, stream>>>(
      x, agg, ow1, ow2, ow3, ob3, og1, obe1, og2, obe2, stats, out);
}

// Round 2
// 1480.942 us; speedup vs baseline: 3.4448x; 3.4448x over previous
//
#include <hip/hip_runtime.h>

// NNConv particle GNN, factored:
//   T[n,h,o] = sum_i x[n,i] * w3[h, i*16+o]   (node-level, kills 16x edge FLOPs)
//   msg[e,o] = sum_h h2[e,h] * T[src,h,o] + xb[src,o]
// BN (training mode) => linear biases b1/b2/own_b1/own_b2 cancel exactly.
// Stats kernels: LDS z-tile + role-switch reduction (2 persistent regs/thread)
// to avoid the round-1 register-spill disaster (was 4.8 GB scratch traffic).

#define N_NODES 50000
#define N_EDGES 800000
#define SD 32
#define OC 16
#define HID 32
#define BN_EPS 1e-5f
#define ETILES 3125   // 800000/256
#define NTILES 196    // ceil(50000/256)

__device__ __forceinline__ float f4get(const float4& v, int ii) {
  return ii == 0 ? v.x : ii == 1 ? v.y : ii == 2 ? v.z : v.w;
}

// z[0..31] += (4*I4-row chunk starting at w-row IOFF) dotted with rp rows
template<int I4, int IOFF>
__device__ __forceinline__ void mv_acc(const float4* __restrict__ rp,
                                       const float* __restrict__ wlds,
                                       float z[HID]) {
#pragma unroll
  for (int i4 = 0; i4 < I4; ++i4) {
    float4 rv = rp[i4];
#pragma unroll
    for (int ii = 0; ii < 4; ++ii) {
      float s = f4get(rv, ii);
      const float* wrow = wlds + (IOFF + i4 * 4 + ii) * HID;
#pragma unroll
      for (int h4 = 0; h4 < HID / 4; ++h4) {
        float4 wv = *reinterpret_cast<const float4*>(wrow + h4 * 4);
        z[h4 * 4 + 0] = fmaf(s, wv.x, z[h4 * 4 + 0]);
        z[h4 * 4 + 1] = fmaf(s, wv.y, z[h4 * 4 + 1]);
        z[h4 * 4 + 2] = fmaf(s, wv.z, z[h4 * 4 + 2]);
        z[h4 * 4 + 3] = fmaf(s, wv.w, z[h4 * 4 + 3]);
      }
    }
  }
}

// z = v(32-vector in regs) @ w (32x32 in LDS)
__device__ __forceinline__ void mv_reg(const float* __restrict__ v,
                                       const float* __restrict__ wlds,
                                       float z[HID]) {
#pragma unroll
  for (int h = 0; h < HID; ++h) z[h] = 0.f;
#pragma unroll
  for (int i = 0; i < HID; ++i) {
    float s = v[i];
    const float* wrow = wlds + i * HID;
#pragma unroll
    for (int h4 = 0; h4 < HID / 4; ++h4) {
      float4 wv = *reinterpret_cast<const float4*>(wrow + h4 * 4);
      z[h4 * 4 + 0] = fmaf(s, wv.x, z[h4 * 4 + 0]);
      z[h4 * 4 + 1] = fmaf(s, wv.y, z[h4 * 4 + 1]);
      z[h4 * 4 + 2] = fmaf(s, wv.z, z[h4 * 4 + 2]);
      z[h4 * 4 + 3] = fmaf(s, wv.w, z[h4 * 4 + 3]);
    }
  }
}

// per-block BN scale/shift from accumulated raw stats (biases cancelled)
__device__ __forceinline__ void bn_params(const float* __restrict__ stats, int off,
                                          float cntInv, const float* __restrict__ g,
                                          const float* __restrict__ be,
                                          float* __restrict__ sc, float* __restrict__ sf) {
  if (threadIdx.x < HID) {
    int h = threadIdx.x;
    float mean = stats[off + h] * cntInv;
    float var = stats[off + HID + h] * cntInv - mean * mean;
    float s = g[h] * rsqrtf(var + BN_EPS);
    sc[h] = s;
    sf[h] = fmaf(-mean, s, be[h]);
  }
}

// tile-based stats epilogue: write z -> tile, role-switch accumulate into (s,q)
__device__ __forceinline__ void tile_accum(const float z[HID], float* __restrict__ tile,
                                           int h, int g, float& s, float& q) {
  int tid = threadIdx.x;
  __syncthreads();   // previous tile reads done before overwrite
#pragma unroll
  for (int j = 0; j < HID; ++j) tile[tid * 33 + j] = z[j];
  __syncthreads();
#pragma unroll
  for (int k = 0; k < 32; ++k) {
    float v = tile[(g * 32 + k) * 33 + h];
    s += v;
    q = fmaf(v, v, q);
  }
}

// final: cross-group reduce (8 groups) + 64 atomics into stats slot
__device__ __forceinline__ void tile_finish(float* __restrict__ tile, int h, int g,
                                            float s, float q,
                                            float* __restrict__ gstats) {
  int tid = threadIdx.x;
  __syncthreads();
  tile[g * 32 + h] = s;
  tile[256 + g * 32 + h] = q;
  __syncthreads();
  if (tid < 64) {
    int hh = tid & 31;
    int base = (tid < 32) ? 0 : 256;
    float acc = 0.f;
#pragma unroll
    for (int g2 = 0; g2 < 8; ++g2) acc += tile[base + g2 * 32 + hh];
    atomicAdd(gstats + ((tid < 32) ? hh : (HID + hh)), acc);
  }
}

// ---------------------------------------------------------------------------
// K0: per-node T [N,32,16], xb = x@b3-reshaped, agg init = x@root_w + root_b
__global__ __launch_bounds__(256) void k0_nodes(
    const float* __restrict__ x, const float* __restrict__ w3,
    const float* __restrict__ b3, const float* __restrict__ rootw,
    const float* __restrict__ rootb, float* __restrict__ T,
    float* __restrict__ xb, float* __restrict__ agg) {
  __shared__ float xs[16][33];
  int n0 = blockIdx.x * 16;
  for (int f = threadIdx.x; f < 16 * SD; f += 256) {
    int nl = f >> 5, i = f & 31;
    int n = n0 + nl;
    xs[nl][i] = (n < N_NODES) ? x[(size_t)n * SD + i] : 0.f;
  }
  __syncthreads();
  int oH = threadIdx.x & 1;
  int h = (threadIdx.x >> 1) & 31;
  int ng = threadIdx.x >> 6;
  float acc[4][8];
#pragma unroll
  for (int k = 0; k < 4; ++k)
#pragma unroll
    for (int j = 0; j < 8; ++j) acc[k][j] = 0.f;
  const float* wbase = w3 + h * (SD * OC) + oH * 8;
#pragma unroll
  for (int i = 0; i < SD; ++i) {
    float4 wa = *reinterpret_cast<const float4*>(wbase + i * OC);
    float4 wb = *reinterpret_cast<const float4*>(wbase + i * OC + 4);
#pragma unroll
    for (int k = 0; k < 4; ++k) {
      float xv = xs[ng * 4 + k][i];
      acc[k][0] = fmaf(xv, wa.x, acc[k][0]);
      acc[k][1] = fmaf(xv, wa.y, acc[k][1]);
      acc[k][2] = fmaf(xv, wa.z, acc[k][2]);
      acc[k][3] = fmaf(xv, wa.w, acc[k][3]);
      acc[k][4] = fmaf(xv, wb.x, acc[k][4]);
      acc[k][5] = fmaf(xv, wb.y, acc[k][5]);
      acc[k][6] = fmaf(xv, wb.z, acc[k][6]);
      acc[k][7] = fmaf(xv, wb.w, acc[k][7]);
    }
  }
#pragma unroll
  for (int k = 0; k < 4; ++k) {
    int n = n0 + ng * 4 + k;
    if (n < N_NODES) {
      float4* dstp = reinterpret_cast<float4*>(T + (size_t)n * (HID * OC) + h * OC + oH * 8);
      dstp[0] = make_float4(acc[k][0], acc[k][1], acc[k][2], acc[k][3]);
      dstp[1] = make_float4(acc[k][4], acc[k][5], acc[k][6], acc[k][7]);
    }
  }
  int nl = threadIdx.x >> 4, o = threadIdx.x & 15;
  int n = n0 + nl;
  if (n < N_NODES) {
    float a1 = 0.f, a2 = 0.f;
#pragma unroll
    for (int i = 0; i < SD; ++i) {
      float xv = xs[nl][i];
      a1 = fmaf(xv, b3[i * OC + o], a1);
      a2 = fmaf(xv, rootw[i * OC + o], a2);
    }
    xb[(size_t)n * OC + o] = a1;
    agg[(size_t)n * OC + o] = a2 + rootb[o];
  }
}

// ---------------------------------------------------------------------------
// S1e: msg-MLP layer1 pre-activation stats -> slot 0
__global__ __launch_bounds__(256) void s1_edge(
    const float* __restrict__ ea, const float* __restrict__ w1,
    float* __restrict__ stats) {
  __shared__ float w1s[SD * HID];
  __shared__ float tile[256 * 33];
  for (int f = threadIdx.x; f < SD * HID; f += 256) w1s[f] = w1[f];
  int h = threadIdx.x & 31, g = threadIdx.x >> 5;
  float s = 0.f, q = 0.f;
  __syncthreads();
#pragma unroll 1
  for (int t = blockIdx.x; t < ETILES; t += gridDim.x) {
    int e = t * 256 + threadIdx.x;
    const float4* rp = reinterpret_cast<const float4*>(ea + (size_t)e * SD);
    float z[HID];
#pragma unroll
    for (int j = 0; j < HID; ++j) z[j] = 0.f;
    mv_acc<8, 0>(rp, w1s, z);
    tile_accum(z, tile, h, g, s, q);
  }
  tile_finish(tile, h, g, s, q, stats + 0);
}

// S2e: recompute layer1 (+BN1+ReLU), layer2 pre-activation stats -> slot 1
__global__ __launch_bounds__(256) void s2_edge(
    const float* __restrict__ ea, const float* __restrict__ w1,
    const float* __restrict__ w2, const float* __restrict__ g1,
    const float* __restrict__ be1, float* __restrict__ stats) {
  __shared__ float w1s[SD * HID], w2s[HID * HID];
  __shared__ float sc1[HID], sf1[HID];
  __shared__ float tile[256 * 33];
  for (int f = threadIdx.x; f < SD * HID; f += 256) w1s[f] = w1[f];
  for (int f = threadIdx.x; f < HID * HID; f += 256) w2s[f] = w2[f];
  bn_params(stats, 0, 1.f / N_EDGES, g1, be1, sc1, sf1);
  int h = threadIdx.x & 31, g = threadIdx.x >> 5;
  float s = 0.f, q = 0.f;
  __syncthreads();
#pragma unroll 1
  for (int t = blockIdx.x; t < ETILES; t += gridDim.x) {
    int e = t * 256 + threadIdx.x;
    const float4* rp = reinterpret_cast<const float4*>(ea + (size_t)e * SD);
    float z1[HID];
#pragma unroll
    for (int j = 0; j < HID; ++j) z1[j] = 0.f;
    mv_acc<8, 0>(rp, w1s, z1);
#pragma unroll
    for (int i = 0; i < HID; ++i) z1[i] = fmaxf(0.f, fmaf(z1[i], sc1[i], sf1[i]));
    float z2[HID];
    mv_reg(z1, w2s, z2);
    tile_accum(z2, tile, h, g, s, q);
  }
  tile_finish(tile, h, g, s, q, stats + 64);
}

// ---------------------------------------------------------------------------
// K5: full edge message, msg = h2 @ T[src] + xb[src], atomic scatter to agg[dst]
__global__ __launch_bounds__(256) void k5_edge_msg(
    const float* __restrict__ ea, const int* __restrict__ ei,
    const float* __restrict__ w1, const float* __restrict__ w2,
    const float* __restrict__ g1, const float* __restrict__ be1,
    const float* __restrict__ g2, const float* __restrict__ be2,
    const float* __restrict__ T, const float* __restrict__ xb,
    const float* __restrict__ stats, float* __restrict__ agg) {
  __shared__ float w1s[SD * HID], w2s[HID * HID];
  __shared__ float sc1[HID], sf1[HID], sc2[HID], sf2[HID];
  for (int f = threadIdx.x; f < SD * HID; f += 256) w1s[f] = w1[f];
  for (int f = threadIdx.x; f < HID * HID; f += 256) w2s[f] = w2[f];
  bn_params(stats, 0, 1.f / N_EDGES, g1, be1, sc1, sf1);
  bn_params(stats, 64, 1.f / N_EDGES, g2, be2, sc2, sf2);
  __syncthreads();
  int e = blockIdx.x * 256 + threadIdx.x;
  if (e >= N_EDGES) return;
  const float4* rp = reinterpret_cast<const float4*>(ea + (size_t)e * SD);
  float z1[HID];
#pragma unroll
  for (int j = 0; j < HID; ++j) z1[j] = 0.f;
  mv_acc<8, 0>(rp, w1s, z1);
#pragma unroll
  for (int i = 0; i < HID; ++i) z1[i] = fmaxf(0.f, fmaf(z1[i], sc1[i], sf1[i]));
  float z2[HID];
  mv_reg(z1, w2s, z2);
#pragma unroll
  for (int i = 0; i < HID; ++i) z2[i] = fmaxf(0.f, fmaf(z2[i], sc2[i], sf2[i]));
  int src = ei[e];
  int dst = ei[N_EDGES + e];
  const float4* Trow = reinterpret_cast<const float4*>(T + (size_t)src * (HID * OC));
  const float4* xbr = reinterpret_cast<const float4*>(xb + (size_t)src * OC);
  float msg[OC];
#pragma unroll
  for (int o4 = 0; o4 < 4; ++o4) {
    float4 b = xbr[o4];
    msg[o4 * 4 + 0] = b.x; msg[o4 * 4 + 1] = b.y;
    msg[o4 * 4 + 2] = b.z; msg[o4 * 4 + 3] = b.w;
  }
#pragma unroll
  for (int hh = 0; hh < HID; ++hh) {
    float hv = z2[hh];
#pragma unroll
    for (int o4 = 0; o4 < 4; ++o4) {
      float4 tv = Trow[hh * 4 + o4];
      msg[o4 * 4 + 0] = fmaf(hv, tv.x, msg[o4 * 4 + 0]);
      msg[o4 * 4 + 1] = fmaf(hv, tv.y, msg[o4 * 4 + 1]);
      msg[o4 * 4 + 2] = fmaf(hv, tv.z, msg[o4 * 4 + 2]);
      msg[o4 * 4 + 3] = fmaf(hv, tv.w, msg[o4 * 4 + 3]);
    }
  }
  float* arow = agg + (size_t)dst * OC;
#pragma unroll
  for (int o = 0; o < OC; ++o) atomicAdd(arow + o, msg[o]);
}

// ---------------------------------------------------------------------------
// S1o: own-MLP layer1 stats over nodes (combined = [x || messages]) -> slot 2
__global__ __launch_bounds__(256) void s1_own(
    const float* __restrict__ x, const float* __restrict__ msgs,
    const float* __restrict__ w1, float* __restrict__ stats) {
  __shared__ float w1s[(SD + OC) * HID];
  __shared__ float tile[256 * 33];
  for (int f = threadIdx.x; f < (SD + OC) * HID; f += 256) w1s[f] = w1[f];
  int h = threadIdx.x & 31, g = threadIdx.x >> 5;
  float s = 0.f, q = 0.f;
  __syncthreads();
#pragma unroll 1
  for (int t = blockIdx.x; t < NTILES; t += gridDim.x) {
    int n = t * 256 + threadIdx.x;
    float z[HID];
#pragma unroll
    for (int j = 0; j < HID; ++j) z[j] = 0.f;
    if (n < N_NODES) {
      const float4* xp = reinterpret_cast<const float4*>(x + (size_t)n * SD);
      const float4* mp = reinterpret_cast<const float4*>(msgs + (size_t)n * OC);
      mv_acc<8, 0>(xp, w1s, z);
      mv_acc<4, SD>(mp, w1s, z);
    }
    tile_accum(z, tile, h, g, s, q);
  }
  tile_finish(tile, h, g, s, q, stats + 128);
}

// S2o: own layer1 (+BN+ReLU) recompute, layer2 stats -> slot 3
__global__ __launch_bounds__(256) void s2_own(
    const float* __restrict__ x, const float* __restrict__ msgs,
    const float* __restrict__ w1, const float* __restrict__ w2,
    const float* __restrict__ g1, const float* __restrict__ be1,
    float* __restrict__ stats) {
  __shared__ float w1s[(SD + OC) * HID], w2s[HID * HID];
  __shared__ float sc1[HID], sf1[HID];
  __shared__ float tile[256 * 33];
  for (int f = threadIdx.x; f < (SD + OC) * HID; f += 256) w1s[f] = w1[f];
  for (int f = threadIdx.x; f < HID * HID; f += 256) w2s[f] = w2[f];
  bn_params(stats, 128, 1.f / N_NODES, g1, be1, sc1, sf1);
  int h = threadIdx.x & 31, g = threadIdx.x >> 5;
  float s = 0.f, q = 0.f;
  __syncthreads();
#pragma unroll 1
  for (int t = blockIdx.x; t < NTILES; t += gridDim.x) {
    int n = t * 256 + threadIdx.x;
    float z2[HID];
#pragma unroll
    for (int j = 0; j < HID; ++j) z2[j] = 0.f;
    if (n < N_NODES) {
      const float4* xp = reinterpret_cast<const float4*>(x + (size_t)n * SD);
      const float4* mp = reinterpret_cast<const float4*>(msgs + (size_t)n * OC);
      float z1[HID];
#pragma unroll
      for (int j = 0; j < HID; ++j) z1[j] = 0.f;
      mv_acc<8, 0>(xp, w1s, z1);
      mv_acc<4, SD>(mp, w1s, z1);
#pragma unroll
      for (int i = 0; i < HID; ++i) z1[i] = fmaxf(0.f, fmaf(z1[i], sc1[i], sf1[i]));
      mv_reg(z1, w2s, z2);
    }
    tile_accum(z2, tile, h, g, s, q);
  }
  tile_finish(tile, h, g, s, q, stats + 192);
}

// ---------------------------------------------------------------------------
// K10: full own-MLP recompute + final linear (own_b3 kept) -> out
__global__ __launch_bounds__(256) void k10_own_out(
    const float* __restrict__ x, const float* __restrict__ msgs,
    const float* __restrict__ w1, const float* __restrict__ w2,
    const float* __restrict__ w3o, const float* __restrict__ b3o,
    const float* __restrict__ g1, const float* __restrict__ be1,
    const float* __restrict__ g2, const float* __restrict__ be2,
    const float* __restrict__ stats, float* __restrict__ out) {
  __shared__ float w1s[(SD + OC) * HID], w2s[HID * HID], w3s[HID * SD];
  __shared__ float sc1[HID], sf1[HID], sc2[HID], sf2[HID];
  for (int f = threadIdx.x; f < (SD + OC) * HID; f += 256) w1s[f] = w1[f];
  for (int f = threadIdx.x; f < HID * HID; f += 256) w2s[f] = w2[f];
  for (int f = threadIdx.x; f < HID * SD; f += 256) w3s[f] = w3o[f];
  bn_params(stats, 128, 1.f / N_NODES, g1, be1, sc1, sf1);
  bn_params(stats, 192, 1.f / N_NODES, g2, be2, sc2, sf2);
  __syncthreads();
  int n = blockIdx.x * 256 + threadIdx.x;
  if (n >= N_NODES) return;
  const float4* xp = reinterpret_cast<const float4*>(x + (size_t)n * SD);
  const float4* mp = reinterpret_cast<const float4*>(msgs + (size_t)n * OC);
  float z1[HID];
#pragma unroll
  for (int j = 0; j < HID; ++j) z1[j] = 0.f;
  mv_acc<8, 0>(xp, w1s, z1);
  mv_acc<4, SD>(mp, w1s, z1);
#pragma unroll
  for (int i = 0; i < HID; ++i) z1[i] = fmaxf(0.f, fmaf(z1[i], sc1[i], sf1[i]));
  float z2[HID];
  mv_reg(z1, w2s, z2);
#pragma unroll
  for (int i = 0; i < HID; ++i) z2[i] = fmaxf(0.f, fmaf(z2[i], sc2[i], sf2[i]));
  float z3[HID];
  mv_reg(z2, w3s, z3);
  float4* op = reinterpret_cast<float4*>(out + (size_t)n * SD);
#pragma unroll
  for (int j4 = 0; j4 < 8; ++j4) {
    op[j4] = make_float4(z3[j4 * 4 + 0] + b3o[j4 * 4 + 0],
                         z3[j4 * 4 + 1] + b3o[j4 * 4 + 1],
                         z3[j4 * 4 + 2] + b3o[j4 * 4 + 2],
                         z3[j4 * 4 + 3] + b3o[j4 * 4 + 3]);
  }
}

extern "C" void kernel_launch(void* const* d_in, const int* in_sizes, int n_in,
                              void* d_out, int out_size, void* d_ws, size_t ws_size,
                              hipStream_t stream) {
  const float* x    = (const float*)d_in[0];
  const float* ea   = (const float*)d_in[1];
  const int*   ei   = (const int*)d_in[2];
  const float* mw1  = (const float*)d_in[3];
  const float* mg1  = (const float*)d_in[5];
  const float* mbe1 = (const float*)d_in[6];
  const float* mw2  = (const float*)d_in[7];
  const float* mg2  = (const float*)d_in[9];
  const float* mbe2 = (const float*)d_in[10];
  const float* mw3  = (const float*)d_in[11];
  const float* mb3  = (const float*)d_in[12];
  const float* rw   = (const float*)d_in[13];
  const float* rb   = (const float*)d_in[14];
  const float* ow1  = (const float*)d_in[15];
  const float* og1  = (const float*)d_in[17];
  const float* obe1 = (const float*)d_in[18];
  const float* ow2  = (const float*)d_in[19];
  const float* og2  = (const float*)d_in[21];
  const float* obe2 = (const float*)d_in[22];
  const float* ow3  = (const float*)d_in[23];
  const float* ob3  = (const float*)d_in[24];
  float* out = (float*)d_out;

  float* wsf = (float*)d_ws;
  float* stats = wsf;                            // 256 floats (4 slots x sum/sumsq)
  float* T = wsf + 256;                          // [N,32,16]
  float* xb = T + (size_t)N_NODES * HID * OC;    // [N,16]
  float* agg = xb + (size_t)N_NODES * OC;        // [N,16]

  hipMemsetAsync(stats, 0, 256 * sizeof(float), stream);

  k0_nodes<<<3125, 256, 0, stream>>>(x, mw3, mb3, rw, rb, T, xb, agg);
  s1_edge<<<1024, 256, 0, stream>>>(ea, mw1, stats);
  s2_edge<<<1024, 256, 0, stream>>>(ea, mw1, mw2, mg1, mbe1, stats);
  k5_edge_msg<<<(N_EDGES + 255) / 256, 256, 0, stream>>>(
      ea, ei, mw1, mw2, mg1, mbe1, mg2, mbe2, T, xb, stats, agg);
  s1_own<<<NTILES, 256, 0, stream>>>(x, agg, ow1, stats);
  s2_own<<<NTILES, 256, 0, stream>>>(x, agg, ow1, ow2, og1, obe1, stats);
  k10_own_out<<<(N_NODES + 255) / 256, 256, 0, stream>>>(
      x, agg, ow1, ow2, ow3, ob3, og1, obe1, og2, obe2, stats, out);
}

// Round 3
// 739.762 us; speedup vs baseline: 6.8961x; 2.0019x over previous
//
#include <hip/hip_runtime.h>
#include <hip/hip_fp16.h>

// NNConv particle GNN, factored + dual counting-sort:
//   T[n,h,o] = sum_i x[n,i]*w3[h,i*16+o]  computed PER-BLOCK in LDS (no T array)
//   msg[e,o] = sum_h h2[e,h]*T[src,h,o] + xb[src,o]
//   src-sorted edge processing (coalesced h2 reuse of T), dst-sorted msg buffer
//   (segment-sum instead of 12.8M global atomics).
// BN training mode => linear biases b1/b2/own_b1/own_b2 cancel exactly.

#define N_NODES 50000
#define N_EDGES 800000
#define SD 32
#define OC 16
#define HID 32
#define BN_EPS 1e-5f
#define ETILES 3125   // 800000/256
#define NTILES 196    // ceil(50000/256)

// ---- workspace byte offsets (all 64B-aligned), total 90,801,152 B ----
#define OFF_STATS 0u          // 256 f
#define OFF_DEGS  1024u       // 50000 i
#define OFF_CURS  201024u     // 50000 i
#define OFF_DEGD  401024u     // 50000 i
#define OFF_CURD  601024u     // 50000 i   [zero 0..801024)
#define OFF_BASES 801024u     // 50001 i
#define OFF_BASED 1001088u    // 50001 i
#define OFF_PERM  1201152u    // 800000 i
#define OFF_POSD  4401152u    // 800000 i
#define OFF_XB    7601152u    // 800000 f
#define OFF_AGG   10801152u   // 800000 f
#define OFF_H2S   14001152u   // 25.6M half
#define OFF_MSGB  65201152u   // 12.8M half

__device__ __forceinline__ float f4get(const float4& v, int ii) {
  return ii == 0 ? v.x : ii == 1 ? v.y : ii == 2 ? v.z : v.w;
}

__device__ __forceinline__ unsigned pack2(float a, float b) {
  __half2 h = __floats2half2_rn(a, b);
  return *reinterpret_cast<unsigned*>(&h);
}
__device__ __forceinline__ void unpk8(uint4 u, float* o) {
  __half2 a = *reinterpret_cast<__half2*>(&u.x), b = *reinterpret_cast<__half2*>(&u.y);
  __half2 c = *reinterpret_cast<__half2*>(&u.z), d = *reinterpret_cast<__half2*>(&u.w);
  float2 fa = __half22float2(a), fb = __half22float2(b);
  float2 fc = __half22float2(c), fd = __half22float2(d);
  o[0] = fa.x; o[1] = fa.y; o[2] = fb.x; o[3] = fb.y;
  o[4] = fc.x; o[5] = fc.y; o[6] = fd.x; o[7] = fd.y;
}

template<int I4, int IOFF>
__device__ __forceinline__ void mv_acc(const float4* __restrict__ rp,
                                       const float* __restrict__ wlds,
                                       float z[HID]) {
#pragma unroll
  for (int i4 = 0; i4 < I4; ++i4) {
    float4 rv = rp[i4];
#pragma unroll
    for (int ii = 0; ii < 4; ++ii) {
      float s = f4get(rv, ii);
      const float* wrow = wlds + (IOFF + i4 * 4 + ii) * HID;
#pragma unroll
      for (int h4 = 0; h4 < HID / 4; ++h4) {
        float4 wv = *reinterpret_cast<const float4*>(wrow + h4 * 4);
        z[h4 * 4 + 0] = fmaf(s, wv.x, z[h4 * 4 + 0]);
        z[h4 * 4 + 1] = fmaf(s, wv.y, z[h4 * 4 + 1]);
        z[h4 * 4 + 2] = fmaf(s, wv.z, z[h4 * 4 + 2]);
        z[h4 * 4 + 3] = fmaf(s, wv.w, z[h4 * 4 + 3]);
      }
    }
  }
}

__device__ __forceinline__ void mv_reg(const float* __restrict__ v,
                                       const float* __restrict__ wlds,
                                       float z[HID]) {
#pragma unroll
  for (int h = 0; h < HID; ++h) z[h] = 0.f;
#pragma unroll
  for (int i = 0; i < HID; ++i) {
    float s = v[i];
    const float* wrow = wlds + i * HID;
#pragma unroll
    for (int h4 = 0; h4 < HID / 4; ++h4) {
      float4 wv = *reinterpret_cast<const float4*>(wrow + h4 * 4);
      z[h4 * 4 + 0] = fmaf(s, wv.x, z[h4 * 4 + 0]);
      z[h4 * 4 + 1] = fmaf(s, wv.y, z[h4 * 4 + 1]);
      z[h4 * 4 + 2] = fmaf(s, wv.z, z[h4 * 4 + 2]);
      z[h4 * 4 + 3] = fmaf(s, wv.w, z[h4 * 4 + 3]);
    }
  }
}

__device__ __forceinline__ void bn_params(const float* __restrict__ stats, int off,
                                          float cntInv, const float* __restrict__ g,
                                          const float* __restrict__ be,
                                          float* __restrict__ sc, float* __restrict__ sf) {
  if (threadIdx.x < HID) {
    int h = threadIdx.x;
    float mean = stats[off + h] * cntInv;
    float var = stats[off + HID + h] * cntInv - mean * mean;
    float s = g[h] * rsqrtf(var + BN_EPS);
    sc[h] = s;
    sf[h] = fmaf(-mean, s, be[h]);
  }
}

__device__ __forceinline__ void tile_accum(const float z[HID], float* __restrict__ tile,
                                           int h, int g, float& s, float& q) {
  int tid = threadIdx.x;
  __syncthreads();
#pragma unroll
  for (int j = 0; j < HID; ++j) tile[tid * 33 + j] = z[j];
  __syncthreads();
#pragma unroll
  for (int k = 0; k < 32; ++k) {
    float v = tile[(g * 32 + k) * 33 + h];
    s += v;
    q = fmaf(v, v, q);
  }
}

__device__ __forceinline__ void tile_finish(float* __restrict__ tile, int h, int g,
                                            float s, float q,
                                            float* __restrict__ gstats) {
  int tid = threadIdx.x;
  __syncthreads();
  tile[g * 32 + h] = s;
  tile[256 + g * 32 + h] = q;
  __syncthreads();
  if (tid < 64) {
    int hh = tid & 31;
    int base = (tid < 32) ? 0 : 256;
    float acc = 0.f;
#pragma unroll
    for (int g2 = 0; g2 < 8; ++g2) acc += tile[base + g2 * 32 + hh];
    atomicAdd(gstats + ((tid < 32) ? hh : (HID + hh)), acc);
  }
}

// ---------------------------------------------------------------------------
// sort infrastructure
__global__ __launch_bounds__(256) void kH(const int* __restrict__ ei,
                                          int* __restrict__ degS, int* __restrict__ degD) {
  int e = blockIdx.x * 256 + threadIdx.x;
  atomicAdd(degS + ei[e], 1);
  atomicAdd(degD + ei[N_EDGES + e], 1);
}

__global__ __launch_bounds__(1024) void kScan(const int* __restrict__ degS, int* __restrict__ baseS,
                                              const int* __restrict__ degD, int* __restrict__ baseD) {
  __shared__ int sc[1024];
  const int* deg = (blockIdx.x == 0) ? degS : degD;
  int* base = (blockIdx.x == 0) ? baseS : baseD;
  int t = threadIdx.x;
  const int C = 49;  // 1024*49 >= 50000
  int st = t * C;
  int sum = 0;
  for (int k = 0; k < C; ++k) {
    int i = st + k;
    if (i < N_NODES) sum += deg[i];
  }
  sc[t] = sum;
  __syncthreads();
  for (int s = 1; s < 1024; s <<= 1) {
    int v = (t >= s) ? sc[t - s] : 0;
    __syncthreads();
    sc[t] += v;
    __syncthreads();
  }
  int run = sc[t] - sum;  // exclusive prefix
  for (int k = 0; k < C; ++k) {
    int i = st + k;
    if (i < N_NODES) { base[i] = run; run += deg[i]; }
  }
  if (t == 1023) base[N_NODES] = run;
}

__global__ __launch_bounds__(256) void kRank(const int* __restrict__ ei,
    const int* __restrict__ baseS, const int* __restrict__ baseD,
    int* __restrict__ curS, int* __restrict__ curD,
    int* __restrict__ perm, int* __restrict__ posD) {
  int e = blockIdx.x * 256 + threadIdx.x;
  int s = ei[e], d = ei[N_EDGES + e];
  int rs = atomicAdd(curS + s, 1);
  perm[baseS[s] + rs] = e;
  int rd = atomicAdd(curD + d, 1);
  posD[e] = baseD[d] + rd;
}

// ---------------------------------------------------------------------------
// K0: xb = x@b3-reshaped, agg init = x@root_w + root_b  (T no longer staged)
__global__ __launch_bounds__(256) void k0_nodes(
    const float* __restrict__ x, const float* __restrict__ b3,
    const float* __restrict__ rootw, const float* __restrict__ rootb,
    float* __restrict__ xb, float* __restrict__ agg) {
  __shared__ float xs[16][33];
  int n0 = blockIdx.x * 16;
  for (int f = threadIdx.x; f < 16 * SD; f += 256) {
    int nl = f >> 5, i = f & 31;
    xs[nl][i] = x[(size_t)(n0 + nl) * SD + i];
  }
  __syncthreads();
  int nl = threadIdx.x >> 4, o = threadIdx.x & 15;
  int n = n0 + nl;
  float a1 = 0.f, a2 = 0.f;
#pragma unroll
  for (int i = 0; i < SD; ++i) {
    float xv = xs[nl][i];
    a1 = fmaf(xv, b3[i * OC + o], a1);
    a2 = fmaf(xv, rootw[i * OC + o], a2);
  }
  xb[(size_t)n * OC + o] = a1;
  agg[(size_t)n * OC + o] = a2 + rootb[o];
}

// ---------------------------------------------------------------------------
// S1e: msg-MLP layer1 pre-activation stats -> slot 0
__global__ __launch_bounds__(256) void s1_edge(
    const float* __restrict__ ea, const float* __restrict__ w1,
    float* __restrict__ stats) {
  __shared__ float w1s[SD * HID];
  __shared__ float tile[256 * 33];
  for (int f = threadIdx.x; f < SD * HID; f += 256) w1s[f] = w1[f];
  int h = threadIdx.x & 31, g = threadIdx.x >> 5;
  float s = 0.f, q = 0.f;
  __syncthreads();
#pragma unroll 1
  for (int t = blockIdx.x; t < ETILES; t += gridDim.x) {
    int e = t * 256 + threadIdx.x;
    const float4* rp = reinterpret_cast<const float4*>(ea + (size_t)e * SD);
    float z[HID];
#pragma unroll
    for (int j = 0; j < HID; ++j) z[j] = 0.f;
    mv_acc<8, 0>(rp, w1s, z);
    tile_accum(z, tile, h, g, s, q);
  }
  tile_finish(tile, h, g, s, q, stats + 0);
}

// S2e: recompute L1 (+BN1+ReLU), L2 pre-act stats -> slot 1; store z2 fp16 (edge order)
__global__ __launch_bounds__(256) void s2_edge(
    const float* __restrict__ ea, const float* __restrict__ w1,
    const float* __restrict__ w2, const float* __restrict__ g1,
    const float* __restrict__ be1, float* __restrict__ stats,
    __half* __restrict__ h2s) {
  __shared__ float w1s[SD * HID], w2s[HID * HID];
  __shared__ float sc1[HID], sf1[HID];
  __shared__ float tile[256 * 33];
  for (int f = threadIdx.x; f < SD * HID; f += 256) w1s[f] = w1[f];
  for (int f = threadIdx.x; f < HID * HID; f += 256) w2s[f] = w2[f];
  bn_params(stats, 0, 1.f / N_EDGES, g1, be1, sc1, sf1);
  int h = threadIdx.x & 31, g = threadIdx.x >> 5;
  float s = 0.f, q = 0.f;
  __syncthreads();
#pragma unroll 1
  for (int t = blockIdx.x; t < ETILES; t += gridDim.x) {
    int e = t * 256 + threadIdx.x;
    const float4* rp = reinterpret_cast<const float4*>(ea + (size_t)e * SD);
    float z1[HID];
#pragma unroll
    for (int j = 0; j < HID; ++j) z1[j] = 0.f;
    mv_acc<8, 0>(rp, w1s, z1);
#pragma unroll
    for (int i = 0; i < HID; ++i) z1[i] = fmaxf(0.f, fmaf(z1[i], sc1[i], sf1[i]));
    float z2[HID];
    mv_reg(z1, w2s, z2);
    // store pre-BN2 z2 as fp16, coalesced (BN2+ReLU applied in k5_gemm)
    unsigned us[16];
#pragma unroll
    for (int q2 = 0; q2 < 16; ++q2) us[q2] = pack2(z2[2 * q2], z2[2 * q2 + 1]);
    uint4* hp = reinterpret_cast<uint4*>(h2s + (size_t)e * HID);
    hp[0] = make_uint4(us[0], us[1], us[2], us[3]);
    hp[1] = make_uint4(us[4], us[5], us[6], us[7]);
    hp[2] = make_uint4(us[8], us[9], us[10], us[11]);
    hp[3] = make_uint4(us[12], us[13], us[14], us[15]);
    tile_accum(z2, tile, h, g, s, q);
  }
  tile_finish(tile, h, g, s, q, stats + 64);
}

// ---------------------------------------------------------------------------
// K5-GEMM: block owns 16 src nodes; T rows computed in LDS; src-sorted slot loop;
// msg -> dst-sorted fp16 buffer (no atomics).
__global__ __launch_bounds__(256) void k5_gemm(
    const float* __restrict__ x, const float* __restrict__ w3,
    const int* __restrict__ perm, const int* __restrict__ posD,
    const int* __restrict__ baseS, const float* __restrict__ xb,
    const __half* __restrict__ h2s, const float* __restrict__ stats,
    const float* __restrict__ g2, const float* __restrict__ be2,
    __half* __restrict__ msgb) {
  __shared__ float Tl[16 * 516];   // [n][o*32+h], pad 4 per row
  __shared__ float xsl[16][33];
  __shared__ float xbl[256];
  __shared__ int bSl[17];
  __shared__ float sc2[HID], sf2[HID];
  int tid = threadIdx.x;
  int n0 = blockIdx.x * 16;
  for (int f = tid; f < 16 * SD; f += 256)
    xsl[f >> 5][f & 31] = x[(size_t)(n0 + (f >> 5)) * SD + (f & 31)];
  xbl[tid] = xb[(size_t)n0 * OC + tid];
  if (tid < 17) bSl[tid] = baseS[n0 + tid];
  bn_params(stats, 64, 1.f / N_EDGES, g2, be2, sc2, sf2);
  __syncthreads();
  // phase 1: Tl[n][o*32+h] = sum_i xsl[n][i] * w3[h, i*16+o]
  {
    int oH = tid & 1, h = (tid >> 1) & 31, ng = tid >> 6;
    float acc[4][8];
#pragma unroll
    for (int k = 0; k < 4; ++k)
#pragma unroll
      for (int j = 0; j < 8; ++j) acc[k][j] = 0.f;
    const float* wbase = w3 + h * (SD * OC) + oH * 8;
#pragma unroll
    for (int i = 0; i < SD; ++i) {
      float4 wa = *reinterpret_cast<const float4*>(wbase + i * OC);
      float4 wb = *reinterpret_cast<const float4*>(wbase + i * OC + 4);
#pragma unroll
      for (int k = 0; k < 4; ++k) {
        float xv = xsl[ng * 4 + k][i];
        acc[k][0] = fmaf(xv, wa.x, acc[k][0]);
        acc[k][1] = fmaf(xv, wa.y, acc[k][1]);
        acc[k][2] = fmaf(xv, wa.z, acc[k][2]);
        acc[k][3] = fmaf(xv, wa.w, acc[k][3]);
        acc[k][4] = fmaf(xv, wb.x, acc[k][4]);
        acc[k][5] = fmaf(xv, wb.y, acc[k][5]);
        acc[k][6] = fmaf(xv, wb.z, acc[k][6]);
        acc[k][7] = fmaf(xv, wb.w, acc[k][7]);
      }
    }
#pragma unroll
    for (int k = 0; k < 4; ++k)
#pragma unroll
      for (int jj = 0; jj < 8; ++jj)
        Tl[(ng * 4 + k) * 516 + (oH * 8 + jj) * 32 + h] = acc[k][jj];
  }
  __syncthreads();
  // phase 2: slots
  int jbeg = bSl[0], jend = bSl[16];
  for (int j = jbeg + tid; j < jend; j += 256) {
    int nl = 0;
    while (j >= bSl[nl + 1]) ++nl;
    int e = perm[j];
    float h2v[HID];
    const uint4* hp = reinterpret_cast<const uint4*>(h2s + (size_t)e * HID);
    uint4 u0 = hp[0], u1 = hp[1], u2 = hp[2], u3 = hp[3];
    unpk8(u0, h2v + 0); unpk8(u1, h2v + 8);
    unpk8(u2, h2v + 16); unpk8(u3, h2v + 24);
#pragma unroll
    for (int k = 0; k < HID; ++k) h2v[k] = fmaxf(0.f, fmaf(h2v[k], sc2[k], sf2[k]));
    float m[OC];
#pragma unroll
    for (int o = 0; o < OC; ++o) m[o] = xbl[nl * 16 + o];
#pragma unroll
    for (int o = 0; o < OC; ++o) {
      const float* tb = Tl + nl * 516 + o * 32;
      float a = m[o];
#pragma unroll
      for (int h4 = 0; h4 < 8; ++h4) {
        float4 t = *reinterpret_cast<const float4*>(tb + h4 * 4);
        a = fmaf(h2v[h4 * 4 + 0], t.x, a);
        a = fmaf(h2v[h4 * 4 + 1], t.y, a);
        a = fmaf(h2v[h4 * 4 + 2], t.z, a);
        a = fmaf(h2v[h4 * 4 + 3], t.w, a);
      }
      m[o] = a;
    }
    int dp = posD[e];
    unsigned us[8];
#pragma unroll
    for (int q = 0; q < 8; ++q) us[q] = pack2(m[2 * q], m[2 * q + 1]);
    uint4* mp = reinterpret_cast<uint4*>(msgb + (size_t)dp * OC);
    mp[0] = make_uint4(us[0], us[1], us[2], us[3]);
    mp[1] = make_uint4(us[4], us[5], us[6], us[7]);
  }
}

// K5-AGGR: exclusive segment-sum of dst-sorted msgs into agg
__global__ __launch_bounds__(256) void k5_aggr(
    const int* __restrict__ baseD, const __half* __restrict__ msgb,
    float* __restrict__ agg) {
  int tid = threadIdx.x;
  int d = blockIdx.x * 16 + (tid >> 4);
  int o = tid & 15;
  int b0 = baseD[d], b1 = baseD[d + 1];
  float s = 0.f;
  for (int j = b0; j < b1; ++j) s += __half2float(msgb[(size_t)j * OC + o]);
  agg[(size_t)d * OC + o] += s;
}

// ---------------------------------------------------------------------------
// own-MLP stats + output (unchanged from round 2)
__global__ __launch_bounds__(256) void s1_own(
    const float* __restrict__ x, const float* __restrict__ msgs,
    const float* __restrict__ w1, float* __restrict__ stats) {
  __shared__ float w1s[(SD + OC) * HID];
  __shared__ float tile[256 * 33];
  for (int f = threadIdx.x; f < (SD + OC) * HID; f += 256) w1s[f] = w1[f];
  int h = threadIdx.x & 31, g = threadIdx.x >> 5;
  float s = 0.f, q = 0.f;
  __syncthreads();
#pragma unroll 1
  for (int t = blockIdx.x; t < NTILES; t += gridDim.x) {
    int n = t * 256 + threadIdx.x;
    float z[HID];
#pragma unroll
    for (int j = 0; j < HID; ++j) z[j] = 0.f;
    if (n < N_NODES) {
      const float4* xp = reinterpret_cast<const float4*>(x + (size_t)n * SD);
      const float4* mp = reinterpret_cast<const float4*>(msgs + (size_t)n * OC);
      mv_acc<8, 0>(xp, w1s, z);
      mv_acc<4, SD>(mp, w1s, z);
    }
    tile_accum(z, tile, h, g, s, q);
  }
  tile_finish(tile, h, g, s, q, stats + 128);
}

__global__ __launch_bounds__(256) void s2_own(
    const float* __restrict__ x, const float* __restrict__ msgs,
    const float* __restrict__ w1, const float* __restrict__ w2,
    const float* __restrict__ g1, const float* __restrict__ be1,
    float* __restrict__ stats) {
  __shared__ float w1s[(SD + OC) * HID], w2s[HID * HID];
  __shared__ float sc1[HID], sf1[HID];
  __shared__ float tile[256 * 33];
  for (int f = threadIdx.x; f < (SD + OC) * HID; f += 256) w1s[f] = w1[f];
  for (int f = threadIdx.x; f < HID * HID; f += 256) w2s[f] = w2[f];
  bn_params(stats, 128, 1.f / N_NODES, g1, be1, sc1, sf1);
  int h = threadIdx.x & 31, g = threadIdx.x >> 5;
  float s = 0.f, q = 0.f;
  __syncthreads();
#pragma unroll 1
  for (int t = blockIdx.x; t < NTILES; t += gridDim.x) {
    int n = t * 256 + threadIdx.x;
    float z2[HID];
#pragma unroll
    for (int j = 0; j < HID; ++j) z2[j] = 0.f;
    if (n < N_NODES) {
      const float4* xp = reinterpret_cast<const float4*>(x + (size_t)n * SD);
      const float4* mp = reinterpret_cast<const float4*>(msgs + (size_t)n * OC);
      float z1[HID];
#pragma unroll
      for (int j = 0; j < HID; ++j) z1[j] = 0.f;
      mv_acc<8, 0>(xp, w1s, z1);
      mv_acc<4, SD>(mp, w1s, z1);
#pragma unroll
      for (int i = 0; i < HID; ++i) z1[i] = fmaxf(0.f, fmaf(z1[i], sc1[i], sf1[i]));
      mv_reg(z1, w2s, z2);
    }
    tile_accum(z2, tile, h, g, s, q);
  }
  tile_finish(tile, h, g, s, q, stats + 192);
}

__global__ __launch_bounds__(256) void k10_own_out(
    const float* __restrict__ x, const float* __restrict__ msgs,
    const float* __restrict__ w1, const float* __restrict__ w2,
    const float* __restrict__ w3o, const float* __restrict__ b3o,
    const float* __restrict__ g1, const float* __restrict__ be1,
    const float* __restrict__ g2, const float* __restrict__ be2,
    const float* __restrict__ stats, float* __restrict__ out) {
  __shared__ float w1s[(SD + OC) * HID], w2s[HID * HID], w3s[HID * SD];
  __shared__ float sc1[HID], sf1[HID], sc2[HID], sf2[HID];
  for (int f = threadIdx.x; f < (SD + OC) * HID; f += 256) w1s[f] = w1[f];
  for (int f = threadIdx.x; f < HID * HID; f += 256) w2s[f] = w2[f];
  for (int f = threadIdx.x; f < HID * SD; f += 256) w3s[f] = w3o[f];
  bn_params(stats, 128, 1.f / N_NODES, g1, be1, sc1, sf1);
  bn_params(stats, 192, 1.f / N_NODES, g2, be2, sc2, sf2);
  __syncthreads();
  int n = blockIdx.x * 256 + threadIdx.x;
  if (n >= N_NODES) return;
  const float4* xp = reinterpret_cast<const float4*>(x + (size_t)n * SD);
  const float4* mp = reinterpret_cast<const float4*>(msgs + (size_t)n * OC);
  float z1[HID];
#pragma unroll
  for (int j = 0; j < HID; ++j) z1[j] = 0.f;
  mv_acc<8, 0>(xp, w1s, z1);
  mv_acc<4, SD>(mp, w1s, z1);
#pragma unroll
  for (int i = 0; i < HID; ++i) z1[i] = fmaxf(0.f, fmaf(z1[i], sc1[i], sf1[i]));
  float z2[HID];
  mv_reg(z1, w2s, z2);
#pragma unroll
  for (int i = 0; i < HID; ++i) z2[i] = fmaxf(0.f, fmaf(z2[i], sc2[i], sf2[i]));
  float z3[HID];
  mv_reg(z2, w3s, z3);
  float4* op = reinterpret_cast<float4*>(out + (size_t)n * SD);
#pragma unroll
  for (int j4 = 0; j4 < 8; ++j4) {
    op[j4] = make_float4(z3[j4 * 4 + 0] + b3o[j4 * 4 + 0],
                         z3[j4 * 4 + 1] + b3o[j4 * 4 + 1],
                         z3[j4 * 4 + 2] + b3o[j4 * 4 + 2],
                         z3[j4 * 4 + 3] + b3o[j4 * 4 + 3]);
  }
}

extern "C" void kernel_launch(void* const* d_in, const int* in_sizes, int n_in,
                              void* d_out, int out_size, void* d_ws, size_t ws_size,
                              hipStream_t stream) {
  const float* x    = (const float*)d_in[0];
  const float* ea   = (const float*)d_in[1];
  const int*   ei   = (const int*)d_in[2];
  const float* mw1  = (const float*)d_in[3];
  const float* mg1  = (const float*)d_in[5];
  const float* mbe1 = (const float*)d_in[6];
  const float* mw2  = (const float*)d_in[7];
  const float* mg2  = (const float*)d_in[9];
  const float* mbe2 = (const float*)d_in[10];
  const float* mw3  = (const float*)d_in[11];
  const float* mb3  = (const float*)d_in[12];
  const float* rw   = (const float*)d_in[13];
  const float* rb   = (const float*)d_in[14];
  const float* ow1  = (const float*)d_in[15];
  const float* og1  = (const float*)d_in[17];
  const float* obe1 = (const float*)d_in[18];
  const float* ow2  = (const float*)d_in[19];
  const float* og2  = (const float*)d_in[21];
  const float* obe2 = (const float*)d_in[22];
  const float* ow3  = (const float*)d_in[23];
  const float* ob3  = (const float*)d_in[24];
  float* out = (float*)d_out;

  char* ws = (char*)d_ws;
  float* stats = (float*)(ws + OFF_STATS);
  int* degS  = (int*)(ws + OFF_DEGS);
  int* curS  = (int*)(ws + OFF_CURS);
  int* degD  = (int*)(ws + OFF_DEGD);
  int* curD  = (int*)(ws + OFF_CURD);
  int* baseS = (int*)(ws + OFF_BASES);
  int* baseD = (int*)(ws + OFF_BASED);
  int* perm  = (int*)(ws + OFF_PERM);
  int* posD  = (int*)(ws + OFF_POSD);
  float* xb  = (float*)(ws + OFF_XB);
  float* agg = (float*)(ws + OFF_AGG);
  __half* h2s  = (__half*)(ws + OFF_H2S);
  __half* msgb = (__half*)(ws + OFF_MSGB);

  // zero stats + deg/cur counters (contiguous region [0, 801024))
  hipMemsetAsync(ws, 0, 801024, stream);

  kH<<<3125, 256, 0, stream>>>(ei, degS, degD);
  kScan<<<2, 1024, 0, stream>>>(degS, baseS, degD, baseD);
  kRank<<<3125, 256, 0, stream>>>(ei, baseS, baseD, curS, curD, perm, posD);
  k0_nodes<<<3125, 256, 0, stream>>>(x, mb3, rw, rb, xb, agg);
  s1_edge<<<1024, 256, 0, stream>>>(ea, mw1, stats);
  s2_edge<<<1024, 256, 0, stream>>>(ea, mw1, mw2, mg1, mbe1, stats, h2s);
  k5_gemm<<<3125, 256, 0, stream>>>(x, mw3, perm, posD, baseS, xb, h2s,
                                    stats, mg2, mbe2, msgb);
  k5_aggr<<<3125, 256, 0, stream>>>(baseD, msgb, agg);
  s1_own<<<NTILES, 256, 0, stream>>>(x, agg, ow1, stats);
  s2_own<<<NTILES, 256, 0, stream>>>(x, agg, ow1, ow2, og1, obe1, stats);
  k10_own_out<<<(N_NODES + 255) / 256, 256, 0, stream>>>(
      x, agg, ow1, ow2, ow3, ob3, og1, obe1, og2, obe2, stats, out);
}